// Round 2
// baseline (1352.871 us; speedup 1.0000x reference)
//
#include <hip/hip_runtime.h>
#include <hip/hip_fp8.h>
#include <stdint.h>

#define N 2560
#define NSUP 640
#define NQ 1920
#define NCLS 128
#define DF 8192
#define CAP 1024
#define TITER 8
#define NBLK 256
#define RPB 10
#define EPSF 2.220446049250313e-16f

typedef __attribute__((ext_vector_type(4))) float f32x4;

// ---------- helpers ----------
__device__ __forceinline__ unsigned short f2bf(float f) {
  unsigned u = __float_as_uint(f);
  return (unsigned short)((u + 0x7FFFu + ((u >> 16) & 1u)) >> 16);  // RNE
}
__device__ __forceinline__ float bf2f(unsigned short h) {
  return __uint_as_float(((unsigned)h) << 16);
}
__device__ __forceinline__ unsigned char f2e4m3(float f) {
  __hip_fp8_e4m3 h(f);                 // OCP e4m3fn on gfx950
  return (unsigned char)h.__x;
}
__device__ __forceinline__ unsigned sortkey(float f) {
  unsigned u = __float_as_uint(f);
  return (u & 0x80000000u) ? ~u : (u | 0x80000000u);
}
__device__ __forceinline__ void load_lds16(const void* g, void* l) {
  __builtin_amdgcn_global_load_lds((const __attribute__((address_space(1))) void*)g,
                                   (__attribute__((address_space(3))) void*)l, 16, 0, 0);
}
// device-scope grid barrier: monotonic counter, release-add + acquire-spin.
// All NBLK blocks are resident by construction (1 block/CU, 41KB LDS).
__device__ __forceinline__ void gridbar(unsigned* cnt, int epoch) {
  __syncthreads();
  if (threadIdx.x == 0) {
    __threadfence();
    __hip_atomic_fetch_add(cnt, 1u, __ATOMIC_RELEASE, __HIP_MEMORY_SCOPE_AGENT);
    while (__hip_atomic_load(cnt, __ATOMIC_ACQUIRE, __HIP_MEMORY_SCOPE_AGENT) <
           (unsigned)(epoch * NBLK)) {
      __builtin_amdgcn_s_sleep(1);
    }
    __threadfence();
  }
  __syncthreads();
}

// ---------- 1. fp32 -> fp8 copy + row sumsq + rho table ----------
__global__ void k_prep(const float* __restrict__ feats, unsigned char* __restrict__ fb8,
                       float* __restrict__ sq, const float* __restrict__ alpha,
                       float* __restrict__ rho_tab) {
  int i = blockIdx.x, t = threadIdx.x;
  const float4* src = (const float4*)(feats + (size_t)i * DF);
  uchar4* dst = (uchar4*)(fb8 + (size_t)i * DF);
  float s = 0.f;
#pragma unroll
  for (int it = 0; it < 8; ++it) {
    float4 v = src[it * 256 + t];
    s = fmaf(v.x, v.x, s); s = fmaf(v.y, v.y, s);
    s = fmaf(v.z, v.z, s); s = fmaf(v.w, v.w, s);
    uchar4 o; o.x = f2e4m3(v.x); o.y = f2e4m3(v.y); o.z = f2e4m3(v.z); o.w = f2e4m3(v.w);
    dst[it * 256 + t] = o;
  }
  __shared__ float red[256];
  red[t] = s; __syncthreads();
  for (int o = 128; o > 0; o >>= 1) { if (t < o) red[t] += red[t + o]; __syncthreads(); }
  if (t == 0) sq[i] = red[0];
  if (i == 0 && t == 0) {  // Chebyshev rho recurrence (theta=1, delta=alpha)
    float a = alpha[0];
    float rho = a; rho_tab[0] = rho;
    for (int k2 = 1; k2 < 128; ++k2) { rho = 1.f / (2.f / a - rho); rho_tab[k2] = rho; }
  }
}

// ---------- 2. C = fb8 @ fb8^T (fp8 MFMA), sym-half + split-K x3, bf16 out ----------
__global__ __launch_bounds__(256, 2) void k_gemm(const unsigned char* __restrict__ fb8,
                                                 unsigned short* __restrict__ C0,
                                                 unsigned short* __restrict__ C1,
                                                 unsigned short* __restrict__ C2) {
  __shared__ __align__(16) unsigned char As[128 * 64];
  __shared__ __align__(16) unsigned char Bs[128 * 64];
  int bid = blockIdx.x;
  int ks = (bid >= 210) + (bid >= 420);
  int tid2 = bid - 210 * ks;
  unsigned short* Cd = (ks == 0) ? C0 : (ks == 1 ? C1 : C2);
  const int kbase = ks * 2752;
  const int kend = kbase + (ks < 2 ? 2752 : 2688);
  int bx = (int)((sqrtf(8.0f * (float)tid2 + 1.0f) - 1.0f) * 0.5f);
  while ((bx + 1) * (bx + 2) / 2 <= tid2) ++bx;
  while (bx * (bx + 1) / 2 > tid2) --bx;
  int by = tid2 - bx * (bx + 1) / 2;           // by <= bx
  const int rA = by * 128, rB = bx * 128;
  const int t = threadIdx.x, w = t >> 6, l = t & 63;
  const int q = l >> 4, m = l & 15;
  const int wr = w >> 1, wc = w & 1;
  f32x4 acc[4][4];
#pragma unroll
  for (int a2 = 0; a2 < 4; ++a2)
#pragma unroll
    for (int b2 = 0; b2 < 4; ++b2) acc[a2][b2] = (f32x4){0.f, 0.f, 0.f, 0.f};

  const int u0 = (w * 2 + 0) * 64 + l;
  const int u1 = (w * 2 + 1) * 64 + l;
  const int row0 = (u0 >> 1) & 127;
  const int ko0 = ((u0 >> 8) << 5) + ((((u0 & 1) ^ ((u0 >> 3) & 1))) << 4);
  const int row1 = (u1 >> 1) & 127;
  const int ko1 = ((u1 >> 8) << 5) + ((((u1 & 1) ^ ((u1 >> 3) & 1))) << 4);
  char* lA0 = (char*)As + (w * 2 + 0) * 1024;  // wave-uniform base (+lane*16 by HW)
  char* lA1 = (char*)As + (w * 2 + 1) * 1024;
  char* lB0 = (char*)Bs + (w * 2 + 0) * 1024;
  char* lB1 = (char*)Bs + (w * 2 + 1) * 1024;
  const int qoff = ((((q >> 1) ^ ((m >> 2) & 1))) << 4) + ((q & 1) << 3);

  for (int k0 = kbase; k0 < kend; k0 += 64) {
    load_lds16(fb8 + (size_t)(rA + row0) * DF + k0 + ko0, lA0);
    load_lds16(fb8 + (size_t)(rA + row1) * DF + k0 + ko1, lA1);
    load_lds16(fb8 + (size_t)(rB + row0) * DF + k0 + ko0, lB0);
    load_lds16(fb8 + (size_t)(rB + row1) * DF + k0 + ko1, lB1);
    asm volatile("s_waitcnt vmcnt(0)" ::: "memory");
    __syncthreads();
#pragma unroll
    for (int s2 = 0; s2 < 2; ++s2) {           // plane s2: 32B-stride rows
      long long af[4], bv[4];
#pragma unroll
      for (int im = 0; im < 4; ++im)
        af[im] = *(const long long*)(As + s2 * 4096 + (wr * 64 + im * 16 + m) * 32 + qoff);
#pragma unroll
      for (int in = 0; in < 4; ++in)
        bv[in] = *(const long long*)(Bs + s2 * 4096 + (wc * 64 + in * 16 + m) * 32 + qoff);
#pragma unroll
      for (int im = 0; im < 4; ++im)
#pragma unroll
        for (int in = 0; in < 4; ++in)
          acc[im][in] = __builtin_amdgcn_mfma_f32_16x16x32_fp8_fp8(
              (long)af[im], (long)bv[in], acc[im][in], 0, 0, 0);
    }
    __syncthreads();
  }
#pragma unroll
  for (int im = 0; im < 4; ++im) {
    int row0w = rA + wr * 64 + im * 16 + q * 4;
#pragma unroll
    for (int in = 0; in < 4; ++in) {
      int col = rB + wc * 64 + in * 16 + m;
#pragma unroll
      for (int rg = 0; rg < 4; ++rg) {
        unsigned short h = f2bf(acc[im][in][rg]);
        Cd[(size_t)(row0w + rg) * N + col] = h;
        Cd[(size_t)col * N + row0w + rg] = h;   // symmetric image
      }
    }
  }
}

// ---------- 3. per-row top-20 (key = 2*(C0+C1+C2) - sq_j, ties -> lower idx) ----------
__global__ void k_topk(const unsigned short* __restrict__ C0,
                       const unsigned short* __restrict__ C1,
                       const unsigned short* __restrict__ C2,
                       const float* __restrict__ sq, unsigned* __restrict__ M) {
  int i = blockIdx.x * 4 + (threadIdx.x >> 6);
  int lane = threadIdx.x & 63;
  const unsigned short* r0 = C0 + (size_t)i * N;
  const unsigned short* r1 = C1 + (size_t)i * N;
  const unsigned short* r2 = C2 + (size_t)i * N;
  unsigned kk[40];
#pragma unroll
  for (int s = 0; s < 40; ++s) {
    int j = lane + (s << 6);
    float c = bf2f(r0[j]) + bf2f(r1[j]) + bf2f(r2[j]);
    kk[s] = sortkey(2.f * c - sq[j]);
  }
  unsigned long long removed = 0ull;
  unsigned myj = 0u;
  for (int t = 0; t < 20; ++t) {
    unsigned bk = 0u; int bs = -1;
#pragma unroll
    for (int s = 0; s < 40; ++s)
      if (!((removed >> s) & 1ull) && kk[s] > bk) { bk = kk[s]; bs = s; }
    unsigned long long packed = (bs < 0) ? 0ull
        : ((((unsigned long long)bk) << 32) |
           (unsigned long long)(0xFFFFFFFFu - (unsigned)(lane + (bs << 6))));
#pragma unroll
    for (int off2 = 32; off2 > 0; off2 >>= 1) {
      unsigned long long o = __shfl_xor(packed, off2, 64);
      if (o > packed) packed = o;
    }
    unsigned jw = 0xFFFFFFFFu - (unsigned)(packed & 0xFFFFFFFFull);
    if ((int)(jw & 63u) == lane) removed |= 1ull << (jw >> 6);
    if (t == lane) myj = jw;
  }
  if (lane < 20) atomicOr(&M[(size_t)i * 80 + (myj >> 5)], 1u << (myj & 31u));
}

// ---------- 4. symmetrize mask, build packed CSR (u16 col | bf16 W), D, dsi ----------
__global__ void k_csr(const unsigned short* __restrict__ C0,
                      const unsigned short* __restrict__ C1,
                      const unsigned short* __restrict__ C2,
                      const float* __restrict__ sq,
                      const unsigned* __restrict__ M, unsigned* __restrict__ csrG,
                      int* __restrict__ degG, float* __restrict__ dsi) {
  int i = blockIdx.x, t = threadIdx.x;
  __shared__ unsigned Mrow[80];
  __shared__ int degs;
  __shared__ unsigned packs[CAP];
  __shared__ float red[256];
  if (t < 80) Mrow[t] = M[(size_t)i * 80 + t];
  if (t == 0) degs = 0;
  __syncthreads();
  const unsigned short* r0c = C0 + (size_t)i * N;
  const unsigned short* r1c = C1 + (size_t)i * N;
  const unsigned short* r2c = C2 + (size_t)i * N;
  float sqi = sq[i];
  int iw = i >> 5; unsigned ib = 1u << (i & 31);
  float dsum = 0.f;
#pragma unroll
  for (int s = 0; s < 10; ++s) {
    int j = t + (s << 8);
    unsigned mij = (Mrow[j >> 5] >> (j & 31)) & 1u;
    unsigned mji = M[(size_t)j * 80 + iw] & ib;
    if (mij | (mji != 0u)) {
      float c = bf2f(r0c[j]) + bf2f(r1c[j]) + bf2f(r2c[j]);
      float wv = expf((2.f * c - sqi - sq[j]) * (1.f / 16384.f));
      int sl = atomicAdd(&degs, 1);
      if (sl < CAP) packs[sl] = (((unsigned)f2bf(wv)) << 16) | (unsigned)j;
      dsum += wv;
    }
  }
  red[t] = dsum; __syncthreads();
  for (int o = 128; o > 0; o >>= 1) { if (t < o) red[t] += red[t + o]; __syncthreads(); }
  if (t == 0) {
    degG[i] = degs > CAP ? CAP : degs;
    dsi[i] = 1.f / sqrtf(red[0] + EPSF);
  }
  __syncthreads();
  int dgc = degs > CAP ? CAP : degs;
  for (int sl = t; sl < dgc; sl += 256)
    csrG[(size_t)i * CAP + sl] = packs[sl];
}

// ---------- 5. fused persistent solver: scale+init + 8 Chebyshev iters + loss ----------
// 256 blocks (1/CU, all resident), wave w of block b owns rows b*10 + {w,w+4,w+8}.
// Edges staged+scaled ONCE into LDS (broadcast reads, no shfl); x,r live in
// registers; only the bf16 d vector round-trips global (cross-block gather).
// Grid barriers: 1 post-init + 8 per-iter + 1 pre-output = 10 epochs.
__global__ __launch_bounds__(256) void k_solve(
    const unsigned* __restrict__ csrG, const int* __restrict__ degG,
    const float* __restrict__ dsi, const float* __restrict__ rho_tab,
    const float* __restrict__ alpha, const int* __restrict__ slab,
    const int* __restrict__ qlab, unsigned short* __restrict__ d0,
    unsigned short* __restrict__ d1, unsigned* __restrict__ barCnt,
    float* __restrict__ lossSum, int* __restrict__ accCnt,
    float* __restrict__ out) {
  __shared__ unsigned ledge[RPB * CAP];   // 40 KB
  __shared__ int ldeg[RPB];
  const int b = blockIdx.x, t = threadIdx.x, w = t >> 6, l = t & 63;
  const int c0 = 2 * l;
  // ---- stage + scale own rows' edges into LDS (wave-private) ----
  for (int lr = w; lr < RPB; lr += 4) {
    int i = b * RPB + lr;
    int dg = degG[i];
    if (l == 0) ldeg[lr] = dg;
    float di = dsi[i];
    for (int s = l; s < dg; s += 64) {
      unsigned p = csrG[(size_t)i * CAP + s];
      int j = p & 0xFFFFu;
      float wv = __uint_as_float(p & 0xFFFF0000u) * di * dsi[j];
      ledge[lr * CAP + s] = (((unsigned)f2bf(wv)) << 16) | (unsigned)j;
    }
  }
  // ---- init x,r (registers) and d0 (global) ----
  float xs0[3], xs1[3], rs0[3], rs1[3];
#pragma unroll
  for (int k2 = 0; k2 < 3; ++k2) {
    int lr = w + 4 * k2;
    xs0[k2] = 0.f; xs1[k2] = 0.f; rs0[k2] = 0.f; rs1[k2] = 0.f;
    if (lr < RPB) {
      int i = b * RPB + lr;
      float y0 = 0.f, y1 = 0.f;
      if (i < NSUP) {
        int lbl = slab[i];
        y0 = (lbl == c0) ? 1.f : 0.f;
        y1 = (lbl == c0 + 1) ? 1.f : 0.f;
      }
      rs0[k2] = y0; rs1[k2] = y1;
      ushort2 dini; dini.x = f2bf(y0); dini.y = f2bf(y1);
      *(ushort2*)(d0 + (size_t)i * NCLS + c0) = dini;
    }
  }
  int epoch = 1;
  gridbar(barCnt, epoch++);
  const float ahat = alpha[0];
  for (int it = 0; it < TITER; ++it) {
    const unsigned short* dc = (it & 1) ? d1 : d0;
    unsigned short* dn = (it & 1) ? d0 : d1;
    float rho = rho_tab[it], rhon = rho_tab[it + 1];
    float cc1 = rhon * rho, cc2 = 2.f * rhon / ahat;
#pragma unroll
    for (int k2 = 0; k2 < 3; ++k2) {
      int lr = w + 4 * k2;
      if (lr >= RPB) continue;
      int i = b * RPB + lr;
      int dg = ldeg[lr];
      const unsigned* er = ledge + lr * CAP;
      float accx = 0.f, accy = 0.f;
      int s = 0;
      for (; s + 8 <= dg; s += 8) {          // 8-deep: 8 independent L2 gathers
        unsigned pp[8]; ushort2 aa[8];
#pragma unroll
        for (int u = 0; u < 8; ++u) pp[u] = er[s + u];   // LDS broadcast
#pragma unroll
        for (int u = 0; u < 8; ++u)
          aa[u] = *(const ushort2*)(dc + (size_t)(pp[u] & 0xFFFFu) * NCLS + c0);
#pragma unroll
        for (int u = 0; u < 8; ++u) {
          float v = __uint_as_float(pp[u] & 0xFFFF0000u);
          accx = fmaf(v, bf2f(aa[u].x), accx);
          accy = fmaf(v, bf2f(aa[u].y), accy);
        }
      }
      for (; s < dg; ++s) {
        unsigned p = er[s];
        ushort2 a = *(const ushort2*)(dc + (size_t)(p & 0xFFFFu) * NCLS + c0);
        float v = __uint_as_float(p & 0xFFFF0000u);
        accx = fmaf(v, bf2f(a.x), accx);
        accy = fmaf(v, bf2f(a.y), accy);
      }
      ushort2 dv = *(const ushort2*)(dc + (size_t)i * NCLS + c0);
      float dix = bf2f(dv.x), diy = bf2f(dv.y);
      float qx = dix - ahat * accx, qy = diy - ahat * accy;
      xs0[k2] += dix; xs1[k2] += diy;
      rs0[k2] -= qx;  rs1[k2] -= qy;
      ushort2 dnn;
      dnn.x = f2bf(cc1 * dix + cc2 * rs0[k2]);
      dnn.y = f2bf(cc1 * diy + cc2 * rs1[k2]);
      *(ushort2*)(dn + (size_t)i * NCLS + c0) = dnn;
    }
    gridbar(barCnt, epoch++);
  }
  // ---- loss + acc from register-resident x ----
#pragma unroll
  for (int k2 = 0; k2 < 3; ++k2) {
    int lr = w + 4 * k2;
    if (lr >= RPB) continue;
    int i = b * RPB + lr;
    float fx = xs0[k2], fy = xs1[k2];
    float mx = fmaxf(fx, fy);
    for (int o2 = 32; o2 > 0; o2 >>= 1) mx = fmaxf(mx, __shfl_xor(mx, o2, 64));
    float se = expf(fx - mx) + expf(fy - mx);
    for (int o2 = 32; o2 > 0; o2 >>= 1) se += __shfl_xor(se, o2, 64);
    float lse = mx + logf(se);
    int gt = (i < NSUP) ? slab[i] : qlab[i - NSUP];
    float fg = ((c0 == gt) ? fx : 0.f) + ((c0 + 1 == gt) ? fy : 0.f);
    for (int o2 = 32; o2 > 0; o2 >>= 1) fg += __shfl_xor(fg, o2, 64);
    if (l == 0) atomicAdd(lossSum, fg - lse);
    if (i >= NSUP) {
      float bvv; int bc;
      if (fy > fx) { bvv = fy; bc = c0 + 1; } else { bvv = fx; bc = c0; }
      unsigned long long packed =
          (((unsigned long long)sortkey(bvv)) << 32) |
          (unsigned long long)(unsigned)(127 - bc);
      for (int o2 = 32; o2 > 0; o2 >>= 1) {
        unsigned long long o = __shfl_xor(packed, o2, 64);
        if (o > packed) packed = o;
      }
      int cw = 127 - (int)(packed & 0xFFFFFFFFull);
      if (l == 0 && cw == qlab[i - NSUP]) atomicAdd(accCnt, 1);
    }
  }
  gridbar(barCnt, epoch++);
  if (b == 0 && t == 0) {
    float ls = __hip_atomic_load(lossSum, __ATOMIC_RELAXED, __HIP_MEMORY_SCOPE_AGENT);
    int ac = __hip_atomic_load(accCnt, __ATOMIC_RELAXED, __HIP_MEMORY_SCOPE_AGENT);
    out[0] = -ls / (float)N;
    out[1] = (float)ac / (float)NQ;
  }
}

// ---------- launch ----------
extern "C" void kernel_launch(void* const* d_in, const int* in_sizes, int n_in,
                              void* d_out, int out_size, void* d_ws, size_t ws_size,
                              hipStream_t stream) {
  const float* feats = (const float*)d_in[0];
  const float* alpha = (const float*)d_in[1];
  const int* slab = (const int*)d_in[2];
  const int* qlab = (const int*)d_in[3];
  float* out = (float*)d_out;
  char* ws = (char*)d_ws;

  // ws layout (bytes). C0/C1/C2 (bf16, 13,107,200 each) die after k_csr;
  // d0/d1 overlay C0. csrG overlays fb8 after k_gemm.
  unsigned short* C0 = (unsigned short*)(ws + 0);
  unsigned short* C1 = (unsigned short*)(ws + 13107200);
  unsigned short* C2 = (unsigned short*)(ws + 26214400);
  unsigned short* d0 = (unsigned short*)(ws + 2621440);   // bf16, 655,360 B
  unsigned short* d1 = (unsigned short*)(ws + 3276800);   // bf16, 655,360 B
  unsigned* M   = (unsigned*)(ws + 39321600);          // 819,200 B bitmask
  float* ctrl   = (float*)(ws + 40140800);             // lossSum, accCnt, barCnt, rho_tab
  float* lossSum = ctrl;
  int* accCnt   = (int*)(ctrl + 1);
  unsigned* barCnt = (unsigned*)(ctrl + 2);
  float* rho_tab = ctrl + 4;                           // 128 floats
  float* sq     = (float*)(ws + 40141824);
  float* dsi    = (float*)(ws + 40152064);
  int* degG     = (int*)(ws + 40162304);
  unsigned char* fb8 = (unsigned char*)(ws + 40172544);   // 20,971,520 B fp8 feats
  unsigned* csrG = (unsigned*)(ws + 40172544);            // overlays fb8 after GEMM
  // total ws required: 61,144,064 bytes

  hipMemsetAsync(ws + 39321600, 0, 820224, stream);    // M + ctrl (incl. barCnt)
  k_prep<<<N, 256, 0, stream>>>(feats, fb8, sq, alpha, rho_tab);
  k_gemm<<<630, 256, 0, stream>>>(fb8, C0, C1, C2);    // lower-tri tiles, split-K x3
  k_topk<<<N / 4, 256, 0, stream>>>(C0, C1, C2, sq, M);
  k_csr<<<N, 256, 0, stream>>>(C0, C1, C2, sq, M, csrG, degG, dsi);
  k_solve<<<NBLK, 256, 0, stream>>>(csrG, degG, dsi, rho_tab, alpha, slab, qlab,
                                    d0, d1, barCnt, lossSum, accCnt, out);
}

// Round 5
// 382.731 us; speedup vs baseline: 3.5348x; 3.5348x over previous
//
#include <hip/hip_runtime.h>
#include <hip/hip_fp8.h>
#include <stdint.h>

#define N 2560
#define NSUP 640
#define NQ 1920
#define NCLS 128
#define DF 8192
#define CAP 1024
#define TITER 8
#define EPSF 2.220446049250313e-16f

typedef __attribute__((ext_vector_type(4))) float f32x4;

// ---------- helpers ----------
__device__ __forceinline__ unsigned short f2bf(float f) {
  unsigned u = __float_as_uint(f);
  return (unsigned short)((u + 0x7FFFu + ((u >> 16) & 1u)) >> 16);  // RNE
}
__device__ __forceinline__ float bf2f(unsigned short h) {
  return __uint_as_float(((unsigned)h) << 16);
}
__device__ __forceinline__ unsigned char f2e4m3(float f) {
  __hip_fp8_e4m3 h(f);                 // OCP e4m3fn on gfx950
  return (unsigned char)h.__x;
}
__device__ __forceinline__ unsigned sortkey(float f) {
  unsigned u = __float_as_uint(f);
  return (u & 0x80000000u) ? ~u : (u | 0x80000000u);
}
__device__ __forceinline__ void load_lds16(const void* g, void* l) {
  __builtin_amdgcn_global_load_lds((const __attribute__((address_space(1))) void*)g,
                                   (__attribute__((address_space(3))) void*)l, 16, 0, 0);
}

// ---------- 1. fp32 -> fp8 copy + row sumsq + rho table ----------
__global__ void k_prep(const float* __restrict__ feats, unsigned char* __restrict__ fb8,
                       float* __restrict__ sq, const float* __restrict__ alpha,
                       float* __restrict__ rho_tab) {
  int i = blockIdx.x, t = threadIdx.x;
  const float4* src = (const float4*)(feats + (size_t)i * DF);
  uchar4* dst = (uchar4*)(fb8 + (size_t)i * DF);
  float s = 0.f;
#pragma unroll
  for (int it = 0; it < 8; ++it) {
    float4 v = src[it * 256 + t];
    s = fmaf(v.x, v.x, s); s = fmaf(v.y, v.y, s);
    s = fmaf(v.z, v.z, s); s = fmaf(v.w, v.w, s);
    uchar4 o; o.x = f2e4m3(v.x); o.y = f2e4m3(v.y); o.z = f2e4m3(v.z); o.w = f2e4m3(v.w);
    dst[it * 256 + t] = o;
  }
  __shared__ float red[256];
  red[t] = s; __syncthreads();
  for (int o = 128; o > 0; o >>= 1) { if (t < o) red[t] += red[t + o]; __syncthreads(); }
  if (t == 0) sq[i] = red[0];
  if (i == 0 && t == 0) {  // Chebyshev rho recurrence (theta=1, delta=alpha)
    float a = alpha[0];
    float rho = a; rho_tab[0] = rho;
    for (int k2 = 1; k2 < 128; ++k2) { rho = 1.f / (2.f / a - rho); rho_tab[k2] = rho; }
  }
}

// ---------- 2. C = fb8 @ fb8^T (fp8 MFMA), sym-half + split-K x3, bf16 out ----------
// 2-phase double-buffered LDS (T3-min template): issue next-tile
// global_load_lds BEFORE computing current tile; ONE vmcnt(0)+barrier per
// K-step (was: load -> vmcnt(0) -> bar -> compute -> bar, full HBM latency
// exposed every tile).
__global__ __launch_bounds__(256, 2) void k_gemm(const unsigned char* __restrict__ fb8,
                                                 unsigned short* __restrict__ C0,
                                                 unsigned short* __restrict__ C1,
                                                 unsigned short* __restrict__ C2) {
  __shared__ __align__(16) unsigned char As[2][128 * 64];
  __shared__ __align__(16) unsigned char Bs[2][128 * 64];
  int bid = blockIdx.x;
  int ks = (bid >= 210) + (bid >= 420);
  int tid2 = bid - 210 * ks;
  unsigned short* Cd = (ks == 0) ? C0 : (ks == 1 ? C1 : C2);
  const int kbase = ks * 2752;
  const int kend = kbase + (ks < 2 ? 2752 : 2688);
  int bx = (int)((sqrtf(8.0f * (float)tid2 + 1.0f) - 1.0f) * 0.5f);
  while ((bx + 1) * (bx + 2) / 2 <= tid2) ++bx;
  while (bx * (bx + 1) / 2 > tid2) --bx;
  int by = tid2 - bx * (bx + 1) / 2;           // by <= bx
  const int rA = by * 128, rB = bx * 128;
  const int t = threadIdx.x, w = t >> 6, l = t & 63;
  const int q = l >> 4, m = l & 15;
  const int wr = w >> 1, wc = w & 1;
  f32x4 acc[4][4];
#pragma unroll
  for (int a2 = 0; a2 < 4; ++a2)
#pragma unroll
    for (int b2 = 0; b2 < 4; ++b2) acc[a2][b2] = (f32x4){0.f, 0.f, 0.f, 0.f};

  // staging chunk u in [0,512): LDS offset u*16. plane=u>>8, row=(u>>1)&127,
  // slot-half=u&1 holds global half (u&1)^((u>>3)&1) -> k-off plane*32+half*16.
  const int u0 = (w * 2 + 0) * 64 + l;
  const int u1 = (w * 2 + 1) * 64 + l;
  const int row0 = (u0 >> 1) & 127;
  const int ko0 = ((u0 >> 8) << 5) + ((((u0 & 1) ^ ((u0 >> 3) & 1))) << 4);
  const int row1 = (u1 >> 1) & 127;
  const int ko1 = ((u1 >> 8) << 5) + ((((u1 & 1) ^ ((u1 >> 3) & 1))) << 4);
  const int so0 = (w * 2 + 0) * 1024;   // wave-uniform LDS offsets (+lane*16 by HW)
  const int so1 = (w * 2 + 1) * 1024;
  // fragment read swizzle: lane-constant half-select (q>>1) ^ ((m>>2)&1)
  const int qoff = ((((q >> 1) ^ ((m >> 2) & 1))) << 4) + ((q & 1) << 3);

  const size_t gA0 = (size_t)(rA + row0) * DF + ko0;
  const size_t gA1 = (size_t)(rA + row1) * DF + ko1;
  const size_t gB0 = (size_t)(rB + row0) * DF + ko0;
  const size_t gB1 = (size_t)(rB + row1) * DF + ko1;

#define STAGE(K0, BUF)                                                  \
  do {                                                                  \
    load_lds16(fb8 + gA0 + (K0), (char*)As[BUF] + so0);                 \
    load_lds16(fb8 + gA1 + (K0), (char*)As[BUF] + so1);                 \
    load_lds16(fb8 + gB0 + (K0), (char*)Bs[BUF] + so0);                 \
    load_lds16(fb8 + gB1 + (K0), (char*)Bs[BUF] + so1);                 \
  } while (0)

  STAGE(kbase, 0);
  asm volatile("s_waitcnt vmcnt(0)" ::: "memory");
  __syncthreads();
  int cur = 0;
  for (int k0 = kbase; k0 < kend; k0 += 64) {
    if (k0 + 64 < kend) STAGE(k0 + 64, cur ^ 1);   // prefetch next tile
    const unsigned char* Ab = As[cur];
    const unsigned char* Bb = Bs[cur];
#pragma unroll
    for (int s2 = 0; s2 < 2; ++s2) {           // plane s2: 32B-stride rows
      long long af[4], bv[4];
#pragma unroll
      for (int im = 0; im < 4; ++im)
        af[im] = *(const long long*)(Ab + s2 * 4096 + (wr * 64 + im * 16 + m) * 32 + qoff);
#pragma unroll
      for (int in = 0; in < 4; ++in)
        bv[in] = *(const long long*)(Bb + s2 * 4096 + (wc * 64 + in * 16 + m) * 32 + qoff);
#pragma unroll
      for (int im = 0; im < 4; ++im)
#pragma unroll
        for (int in = 0; in < 4; ++in)
          acc[im][in] = __builtin_amdgcn_mfma_f32_16x16x32_fp8_fp8(
              (long)af[im], (long)bv[in], acc[im][in], 0, 0, 0);
    }
    asm volatile("s_waitcnt vmcnt(0)" ::: "memory");  // next tile landed
    __syncthreads();                                   // all waves done with cur
    cur ^= 1;
  }
#undef STAGE
#pragma unroll
  for (int im = 0; im < 4; ++im) {
    int row0w = rA + wr * 64 + im * 16 + q * 4;
#pragma unroll
    for (int in = 0; in < 4; ++in) {
      int col = rB + wc * 64 + in * 16 + m;
#pragma unroll
      for (int rg = 0; rg < 4; ++rg) {
        unsigned short h = f2bf(acc[im][in][rg]);
        Cd[(size_t)(row0w + rg) * N + col] = h;
        Cd[(size_t)col * N + row0w + rg] = h;   // symmetric image
      }
    }
  }
}

// ---------- 3. per-row top-20 (key = 2*(C0+C1+C2) - sq_j, ties -> lower idx) ----------
// Also writes transposed mask MT so k_csr's symmetrization read is contiguous
// (was a stride-320B 4B gather, 16x line overfetch). MT must be zeroed AFTER
// k_gemm (it overlays the dead tail of fb8) — see launch order.
__global__ void k_topk(const unsigned short* __restrict__ C0,
                       const unsigned short* __restrict__ C1,
                       const unsigned short* __restrict__ C2,
                       const float* __restrict__ sq, unsigned* __restrict__ M,
                       unsigned* __restrict__ MT) {
  int i = blockIdx.x * 4 + (threadIdx.x >> 6);
  int lane = threadIdx.x & 63;
  const unsigned short* r0 = C0 + (size_t)i * N;
  const unsigned short* r1 = C1 + (size_t)i * N;
  const unsigned short* r2 = C2 + (size_t)i * N;
  unsigned kk[40];
#pragma unroll
  for (int s = 0; s < 40; ++s) {
    int j = lane + (s << 6);
    float c = bf2f(r0[j]) + bf2f(r1[j]) + bf2f(r2[j]);
    kk[s] = sortkey(2.f * c - sq[j]);
  }
  unsigned long long removed = 0ull;
  unsigned myj = 0u;
  for (int t = 0; t < 20; ++t) {
    unsigned bk = 0u; int bs = -1;
#pragma unroll
    for (int s = 0; s < 40; ++s)
      if (!((removed >> s) & 1ull) && kk[s] > bk) { bk = kk[s]; bs = s; }
    unsigned long long packed = (bs < 0) ? 0ull
        : ((((unsigned long long)bk) << 32) |
           (unsigned long long)(0xFFFFFFFFu - (unsigned)(lane + (bs << 6))));
#pragma unroll
    for (int off2 = 32; off2 > 0; off2 >>= 1) {
      unsigned long long o = __shfl_xor(packed, off2, 64);
      if (o > packed) packed = o;
    }
    unsigned jw = 0xFFFFFFFFu - (unsigned)(packed & 0xFFFFFFFFull);
    if ((int)(jw & 63u) == lane) removed |= 1ull << (jw >> 6);
    if (t == lane) myj = jw;
  }
  if (lane < 20) {
    atomicOr(&M[(size_t)i * 80 + (myj >> 5)], 1u << (myj & 31u));
    atomicOr(&MT[(size_t)myj * 80 + (i >> 5)], 1u << (i & 31u));
  }
}

// ---------- 4. symmetrize mask, build packed CSR (u16 col | bf16 W), D, dsi ----------
__global__ void k_csr(const unsigned short* __restrict__ C0,
                      const unsigned short* __restrict__ C1,
                      const unsigned short* __restrict__ C2,
                      const float* __restrict__ sq,
                      const unsigned* __restrict__ M, const unsigned* __restrict__ MT,
                      unsigned* __restrict__ csrG,
                      int* __restrict__ degG, float* __restrict__ dsi) {
  int i = blockIdx.x, t = threadIdx.x;
  __shared__ unsigned Mrow[80];
  __shared__ unsigned MTrow[80];
  __shared__ int degs;
  __shared__ unsigned packs[CAP];
  __shared__ float red[256];
  if (t < 80) Mrow[t] = M[(size_t)i * 80 + t];
  if (t >= 128 && t < 208) MTrow[t - 128] = MT[(size_t)i * 80 + (t - 128)];
  if (t == 0) degs = 0;
  __syncthreads();
  const unsigned short* r0c = C0 + (size_t)i * N;
  const unsigned short* r1c = C1 + (size_t)i * N;
  const unsigned short* r2c = C2 + (size_t)i * N;
  float sqi = sq[i];
  float dsum = 0.f;
#pragma unroll
  for (int s = 0; s < 10; ++s) {
    int j = t + (s << 8);
    unsigned mm = (Mrow[j >> 5] | MTrow[j >> 5]) >> (j & 31);
    if (mm & 1u) {
      float c = bf2f(r0c[j]) + bf2f(r1c[j]) + bf2f(r2c[j]);
      float wv = expf((2.f * c - sqi - sq[j]) * (1.f / 16384.f));
      int sl = atomicAdd(&degs, 1);
      if (sl < CAP) packs[sl] = (((unsigned)f2bf(wv)) << 16) | (unsigned)j;
      dsum += wv;
    }
  }
  red[t] = dsum; __syncthreads();
  for (int o = 128; o > 0; o >>= 1) { if (t < o) red[t] += red[t + o]; __syncthreads(); }
  if (t == 0) {
    degG[i] = degs > CAP ? CAP : degs;
    dsi[i] = 1.f / sqrtf(red[0] + EPSF);
  }
  __syncthreads();
  int dgc = degs > CAP ? CAP : degs;
  for (int sl = t; sl < dgc; sl += 256)
    csrG[(size_t)i * CAP + sl] = packs[sl];
}

// ---------- 5. merged: S edge scaling (in packed CSR) + Chebyshev init ----------
__global__ void k_scale_init(unsigned* __restrict__ csrG, const int* __restrict__ degG,
                             const float* __restrict__ dsi, const int* __restrict__ slab,
                             float* __restrict__ x, float* __restrict__ r,
                             unsigned short* __restrict__ d0) {
  int i = blockIdx.x * 4 + (threadIdx.x >> 6);
  int lane = threadIdx.x & 63;
  float di = dsi[i];
  int dg = degG[i];
  for (int s = lane; s < dg; s += 64) {
    unsigned p = csrG[(size_t)i * CAP + s];
    int j = p & 0xFFFFu;
    float wv = __uint_as_float(p & 0xFFFF0000u);
    wv *= di * dsi[j];
    csrG[(size_t)i * CAP + s] = (((unsigned)f2bf(wv)) << 16) | (unsigned)j;
  }
  int c0 = 2 * lane;
  float y0 = 0.f, y1 = 0.f;
  if (i < NSUP) {
    int lbl = slab[i];
    y0 = (lbl == c0) ? 1.f : 0.f;
    y1 = (lbl == c0 + 1) ? 1.f : 0.f;
  }
  size_t o = (size_t)i * NCLS + c0;
  x[o] = 0.f; x[o + 1] = 0.f;
  r[o] = y0;  r[o + 1] = y1;
  ushort2 dini; dini.x = f2bf(y0); dini.y = f2bf(y1);
  *(ushort2*)(d0 + o) = dini;
}

// ---------- 6. one Chebyshev iteration (A = I - alpha*S), d in bf16 ----------
// Champion structure (16.2 us/iter): block per row, 256 threads,
// g = t&31 (4 classes), p = t>>5 (8 edge partitions), 8-deep unrolled gather.
__global__ __launch_bounds__(256) void k_cheby(const unsigned* __restrict__ csrG,
                        const int* __restrict__ degG, const float* __restrict__ rho_tab,
                        const float* __restrict__ alpha, float* __restrict__ x,
                        float* __restrict__ r, const unsigned short* __restrict__ dcur,
                        unsigned short* __restrict__ dnxt, int it) {
  int i = blockIdx.x;
  int t = threadIdx.x;
  int g4 = (t & 31) << 2, p = t >> 5;
  __shared__ unsigned lcv[CAP];
  __shared__ float4 partial[256];
  int dg = degG[i];
  for (int s = t; s < dg; s += 256) lcv[s] = csrG[(size_t)i * CAP + s];
  __syncthreads();
  float4 acc = make_float4(0.f, 0.f, 0.f, 0.f);
  int s = p;
  for (; s + 56 < dg; s += 64) {         // 8 partitions x 8-deep unroll
    unsigned uu[8]; ushort4 a[8];
#pragma unroll
    for (int u = 0; u < 8; ++u) {
      uu[u] = lcv[s + 8 * u];
      a[u] = *(const ushort4*)(dcur + (size_t)(uu[u] & 0xFFFFu) * NCLS + g4);
    }
#pragma unroll
    for (int u = 0; u < 8; ++u) {
      float v = __uint_as_float(uu[u] & 0xFFFF0000u);
      acc.x = fmaf(v, bf2f(a[u].x), acc.x);
      acc.y = fmaf(v, bf2f(a[u].y), acc.y);
      acc.z = fmaf(v, bf2f(a[u].z), acc.z);
      acc.w = fmaf(v, bf2f(a[u].w), acc.w);
    }
  }
  for (; s < dg; s += 8) {               // tail
    unsigned uu = lcv[s];
    ushort4 a = *(const ushort4*)(dcur + (size_t)(uu & 0xFFFFu) * NCLS + g4);
    float v = __uint_as_float(uu & 0xFFFF0000u);
    acc.x = fmaf(v, bf2f(a.x), acc.x); acc.y = fmaf(v, bf2f(a.y), acc.y);
    acc.z = fmaf(v, bf2f(a.z), acc.z); acc.w = fmaf(v, bf2f(a.w), acc.w);
  }
  partial[t] = acc;
  __syncthreads();
  for (int off = 128; off >= 32; off >>= 1) {
    if (t < off) {
      float4 o = partial[t + off];
      float4 m = partial[t];
      m.x += o.x; m.y += o.y; m.z += o.z; m.w += o.w;
      partial[t] = m;
    }
    __syncthreads();
  }
  if (t < 32) {                          // classes 4t..4t+3
    float4 ax = partial[t];
    float ahat = alpha[0];
    float rho = rho_tab[it], rhon = rho_tab[it + 1];
    float cc1 = rhon * rho, cc2 = 2.f * rhon / ahat;
    size_t o = (size_t)i * NCLS + 4 * t;
    ushort4 dv = *(const ushort4*)(dcur + o);
    float4 di; di.x = bf2f(dv.x); di.y = bf2f(dv.y); di.z = bf2f(dv.z); di.w = bf2f(dv.w);
    float4 xv = *(float4*)(x + o);
    float4 rv = *(float4*)(r + o);
    float4 q;
    q.x = di.x - ahat * ax.x; q.y = di.y - ahat * ax.y;
    q.z = di.z - ahat * ax.z; q.w = di.w - ahat * ax.w;
    xv.x += di.x; xv.y += di.y; xv.z += di.z; xv.w += di.w;
    rv.x -= q.x; rv.y -= q.y; rv.z -= q.z; rv.w -= q.w;
    ushort4 dn;
    dn.x = f2bf(cc1 * di.x + cc2 * rv.x); dn.y = f2bf(cc1 * di.y + cc2 * rv.y);
    dn.z = f2bf(cc1 * di.z + cc2 * rv.z); dn.w = f2bf(cc1 * di.w + cc2 * rv.w);
    *(float4*)(x + o) = xv;
    *(float4*)(r + o) = rv;
    *(ushort4*)(dnxt + o) = dn;
  }
}

// ---------- 7. loss + acc ----------
__global__ void k_loss(const float* __restrict__ F, const int* __restrict__ slab,
                       const int* __restrict__ qlab, float* __restrict__ lossSum,
                       int* __restrict__ accCnt) {
  int i = blockIdx.x * 4 + (threadIdx.x >> 6);
  int lane = threadIdx.x & 63;
  int c0 = 2 * lane;
  float2 f = *(const float2*)(F + (size_t)i * NCLS + c0);
  float mx = fmaxf(f.x, f.y);
  for (int o2 = 32; o2 > 0; o2 >>= 1) mx = fmaxf(mx, __shfl_xor(mx, o2, 64));
  float se = expf(f.x - mx) + expf(f.y - mx);
  for (int o2 = 32; o2 > 0; o2 >>= 1) se += __shfl_xor(se, o2, 64);
  float lse = mx + logf(se);
  int gt = (i < NSUP) ? slab[i] : qlab[i - NSUP];
  float fg = ((c0 == gt) ? f.x : 0.f) + ((c0 + 1 == gt) ? f.y : 0.f);
  for (int o2 = 32; o2 > 0; o2 >>= 1) fg += __shfl_xor(fg, o2, 64);
  if (lane == 0) atomicAdd(lossSum, fg - lse);
  if (i >= NSUP) {
    float bvv; int bc;
    if (f.y > f.x) { bvv = f.y; bc = c0 + 1; } else { bvv = f.x; bc = c0; }
    unsigned long long packed =
        (((unsigned long long)sortkey(bvv)) << 32) | (unsigned long long)(unsigned)(127 - bc);
    for (int o2 = 32; o2 > 0; o2 >>= 1) {
      unsigned long long o = __shfl_xor(packed, o2, 64);
      if (o > packed) packed = o;
    }
    int cw = 127 - (int)(packed & 0xFFFFFFFFull);
    if (lane == 0 && cw == qlab[i - NSUP]) atomicAdd(accCnt, 1);
  }
}

// ---------- 8. finalize ----------
__global__ void k_final(const float* __restrict__ lossSum, const int* __restrict__ accCnt,
                        float* __restrict__ out) {
  out[0] = -lossSum[0] / (float)N;
  out[1] = (float)accCnt[0] / (float)NQ;
}

// ---------- launch ----------
extern "C" void kernel_launch(void* const* d_in, const int* in_sizes, int n_in,
                              void* d_out, int out_size, void* d_ws, size_t ws_size,
                              hipStream_t stream) {
  const float* feats = (const float*)d_in[0];
  const float* alpha = (const float*)d_in[1];
  const int* slab = (const int*)d_in[2];
  const int* qlab = (const int*)d_in[3];
  float* out = (float*)d_out;
  char* ws = (char*)d_ws;

  // ws layout (bytes). C0/C1/C2 (bf16, 13,107,200 each) die after k_csr;
  // x/r/d0/d1 overlay C0. csrG overlays fb8 after k_gemm; MT overlays the
  // tail of dead fb8 space beyond csrG (zeroed only AFTER k_gemm!).
  unsigned short* C0 = (unsigned short*)(ws + 0);
  unsigned short* C1 = (unsigned short*)(ws + 13107200);
  unsigned short* C2 = (unsigned short*)(ws + 26214400);
  float* x           = (float*)(ws + 0);
  float* r           = (float*)(ws + 1310720);
  unsigned short* d0 = (unsigned short*)(ws + 2621440);   // bf16, 655,360 B
  unsigned short* d1 = (unsigned short*)(ws + 3276800);   // bf16, 655,360 B
  unsigned* M   = (unsigned*)(ws + 39321600);          // 819,200 B bitmask
  float* ctrl   = (float*)(ws + 40140800);             // lossSum, accCnt, rho_tab
  float* lossSum = ctrl;
  int* accCnt   = (int*)(ctrl + 1);
  float* rho_tab = ctrl + 4;                           // 128 floats
  float* sq     = (float*)(ws + 40141824);
  float* dsi    = (float*)(ws + 40152064);
  int* degG     = (int*)(ws + 40162304);
  unsigned char* fb8 = (unsigned char*)(ws + 40172544);   // 20,971,520 B fp8 feats
  unsigned* csrG = (unsigned*)(ws + 40172544);            // overlays fb8 after GEMM
  unsigned* MT  = (unsigned*)(ws + 50658304);             // 819,200 B transposed mask
  // total ws required: 61,144,064 bytes

  hipMemsetAsync(ws + 39321600, 0, 820224, stream);    // M + ctrl
  k_prep<<<N, 256, 0, stream>>>(feats, fb8, sq, alpha, rho_tab);
  k_gemm<<<630, 256, 0, stream>>>(fb8, C0, C1, C2);    // lower-tri tiles, split-K x3
  // MT overlays fb8's tail: zero it only after k_gemm has consumed fb8.
  hipMemsetAsync(ws + 50658304, 0, 819200, stream);
  k_topk<<<N / 4, 256, 0, stream>>>(C0, C1, C2, sq, M, MT);
  k_csr<<<N, 256, 0, stream>>>(C0, C1, C2, sq, M, MT, csrG, degG, dsi);
  k_scale_init<<<N / 4, 256, 0, stream>>>(csrG, degG, dsi, slab, x, r, d0);
  for (int it = 0; it < TITER; ++it) {
    const unsigned short* dc = (it & 1) ? d1 : d0;
    unsigned short* dn = (it & 1) ? d0 : d1;
    k_cheby<<<N, 256, 0, stream>>>(csrG, degG, rho_tab, alpha, x, r, dc, dn, it);
  }
  k_loss<<<N / 4, 256, 0, stream>>>(x, slab, qlab, lossSum, accCnt);
  k_final<<<1, 1, 0, stream>>>(lossSum, accCnt, out);
}